// Round 2
// baseline (96.887 us; speedup 1.0000x reference)
//
#include <hip/hip_runtime.h>
#include <math.h>

// Problem constants (from reference)
#define Bb 32
#define Ll 4096
#define Cc 4
#define GG 8          // Bb / GROUP
#define NPAIR 496     // 32*31/2
#define LSPLIT 2      // l-chunks per pair in kernel B

// ws accumulators: acc[0]=ce_sum (sum of logp@label), acc[1]=r2_sum, acc[2]=evo_sum

__device__ __forceinline__ float waveSum(float v) {
#pragma unroll
    for (int o = 32; o > 0; o >>= 1) v += __shfl_down(v, o, 64);
    return v;
}

__global__ __launch_bounds__(256) void kernelA(const float* __restrict__ logits,
                                               const float* __restrict__ prob,
                                               const float* __restrict__ y_true,
                                               float* __restrict__ acc) {
    int t = blockIdx.x * 256 + threadIdx.x;   // t in [0, GG*Ll)
    int l = t & (Ll - 1);
    int g = t >> 12;

    float ce = 0.f;
    float pred_alt[4];
    int cnt = 0;
#pragma unroll
    for (int m = 0; m < 4; ++m) {
        int b = g * 4 + m;
        int base = (b * Ll + l) * 4;
        float4 yt = *reinterpret_cast<const float4*>(y_true + base);
        int lbl = 0; float bv = yt.x;
        if (yt.y > bv) { bv = yt.y; lbl = 1; }
        if (yt.z > bv) { bv = yt.z; lbl = 2; }
        if (yt.w > bv) { bv = yt.w; lbl = 3; }

        float4 x = *reinterpret_cast<const float4*>(logits + base);
        float mx = fmaxf(fmaxf(x.x, x.y), fmaxf(x.z, x.w));
        float s = expf(x.x - mx) + expf(x.y - mx) + expf(x.z - mx) + expf(x.w - mx);
        float xl = (lbl == 0) ? x.x : (lbl == 1) ? x.y : (lbl == 2) ? x.z : x.w;
        ce += (xl - mx) - logf(s);

        float4 p = *reinterpret_cast<const float4*>(prob + base);
        pred_alt[m] = p.y + p.z + p.w;   // sum of channels 1..3
        cnt += (lbl != 0);
    }

    float r2 = 0.f;
    if (cnt != 0 && cnt != 4) {          // non-mono groups only; mono -> 0
        float af = (float)cnt * 0.25f;
        float denom = fmaxf(af * (1.f - af), 0.01f);
        float ssum = 0.f;
#pragma unroll
        for (int m = 0; m < 4; ++m) { float d = pred_alt[m] - af; ssum += d * d; }
        r2 = 0.25f * ssum / denom;       // mean over group members
    }

    __shared__ float sce[4], sr2[4];
    int wid = threadIdx.x >> 6, lane = threadIdx.x & 63;
    float cew = waveSum(ce), r2w = waveSum(r2);
    if (lane == 0) { sce[wid] = cew; sr2[wid] = r2w; }
    __syncthreads();
    if (threadIdx.x == 0) {
        atomicAdd(&acc[0], sce[0] + sce[1] + sce[2] + sce[3]);
        atomicAdd(&acc[1], sr2[0] + sr2[1] + sr2[2] + sr2[3]);
    }
}

__device__ __forceinline__ float js_ch(float p, float q) {
    float mm = 0.5f * (p + q) + 1e-7f;
    float lm = logf(mm);
    return p * (logf(p + 1e-7f) - lm) + q * (logf(q + 1e-7f) - lm);
}

__global__ __launch_bounds__(256) void kernelB(const float* __restrict__ prob,
                                               const float* __restrict__ y_true,
                                               const float* __restrict__ y_evo,
                                               float* __restrict__ acc) {
    int bx = blockIdx.x;
    int pair = bx % NPAIR;
    int chunk = bx / NPAIR;

    // decode pair -> (i,j), i<j
    int i = 0, rem = pair;
    while (rem >= (Bb - 1 - i)) { rem -= (Bb - 1 - i); ++i; }
    int j = i + 1 + rem;

    __shared__ float s_w;
    if (threadIdx.x == 0) {
        float si = 0.f, sj = 0.f;
        for (int k = 0; k < Bb; ++k) {
            si += expf(-y_evo[i * Bb + k]);
            sj += expf(-y_evo[j * Bb + k]);
        }
        s_w = expf(-y_evo[i * Bb + j]) / (si + 1e-8f)
            + expf(-y_evo[j * Bb + i]) / (sj + 1e-8f);
    }
    __syncthreads();

    const int lchunk = Ll / LSPLIT;
    const int l0 = chunk * lchunk;
    float accl = 0.f;
    for (int l = l0 + threadIdx.x; l < l0 + lchunk; l += 256) {
        int bi = (i * Ll + l) * 4, bj = (j * Ll + l) * 4;
        float4 yi = *reinterpret_cast<const float4*>(y_true + bi);
        float4 yj = *reinterpret_cast<const float4*>(y_true + bj);
        float mask = (yi.x == yj.x && yi.y == yj.y && yi.z == yj.z && yi.w == yj.w)
                       ? 1.f : 0.f;
        float4 p = *reinterpret_cast<const float4*>(prob + bi);
        float4 q = *reinterpret_cast<const float4*>(prob + bj);
        float kl = 0.f;
        kl += js_ch(p.x, q.x);
        kl += js_ch(p.y, q.y);
        kl += js_ch(p.z, q.z);
        kl += js_ch(p.w, q.w);
        accl += mask * 0.5f * kl;
    }

    __shared__ float sp[4];
    int wid = threadIdx.x >> 6, lane = threadIdx.x & 63;
    float w = waveSum(accl);
    if (lane == 0) sp[wid] = w;
    __syncthreads();
    if (threadIdx.x == 0) {
        float bsum = sp[0] + sp[1] + sp[2] + sp[3];
        atomicAdd(&acc[2], s_w * bsum);
    }
}

__global__ void kernelF(const float* __restrict__ acc, float* __restrict__ out) {
    float ce_loss = -acc[0];
    float r2_loss = -(acc[1] * 4.f) / (float)Bb;   // R2_WEIGHT * (-sum*GROUP)/B
    float evo = acc[2];
    if (!isfinite(evo)) evo = 0.f;
    out[0] = ce_loss + r2_loss + evo;
}

extern "C" void kernel_launch(void* const* d_in, const int* in_sizes, int n_in,
                              void* d_out, int out_size, void* d_ws, size_t ws_size,
                              hipStream_t stream) {
    const float* logits = (const float*)d_in[0];
    const float* prob   = (const float*)d_in[1];
    const float* y_true = (const float*)d_in[2];
    const float* y_evo  = (const float*)d_in[3];
    float* out = (float*)d_out;
    float* acc = (float*)d_ws;

    hipMemsetAsync(acc, 0, 3 * sizeof(float), stream);
    kernelA<<<(GG * Ll) / 256, 256, 0, stream>>>(logits, prob, y_true, acc);
    kernelB<<<NPAIR * LSPLIT, 256, 0, stream>>>(prob, y_true, y_evo, acc);
    kernelF<<<1, 1, 0, stream>>>(acc, out);
}

// Round 3
// 75.637 us; speedup vs baseline: 1.2809x; 1.2809x over previous
//
#include <hip/hip_runtime.h>
#include <math.h>

#define Bb 32
#define Ll 4096
#define NPAIR 496
#define NBLK_B (NPAIR * 2)   // 2 l-chunks per pair

// ws layout (floats):
//   [0..127]      ceP    (per kernelA block)
//   [128..255]    r2P
//   [256..1247]   evoP   (per kernelB block, 992)
//   [1280..1311]  rowsum (32)
//   [4096..]      ent    (32*4096 floats)
//   bytes after ent: lab (32*4096 u8)
#define ENT_OFF 4096
#define ROWSUM_OFF 1280

__device__ __forceinline__ float waveSum(float v) {
#pragma unroll
    for (int o = 32; o > 0; o >>= 1) v += __shfl_down(v, o, 64);
    return v;
}

__global__ __launch_bounds__(256) void kernelA(const float* __restrict__ logits,
                                               const float* __restrict__ prob,
                                               const float* __restrict__ y_true,
                                               const float* __restrict__ y_evo,
                                               float* __restrict__ W) {
    int t = blockIdx.x * 256 + threadIdx.x;   // t in [0, 8*4096)
    int l = t & (Ll - 1);
    int g = t >> 12;

    float* ent = W + ENT_OFF;
    unsigned char* lab = (unsigned char*)(W + ENT_OFF + Bb * Ll);

    float ce = 0.f;
    float pred_alt[4];
    int cnt = 0;
#pragma unroll
    for (int m = 0; m < 4; ++m) {
        int b = g * 4 + m;
        int base = (b * Ll + l) * 4;
        float4 yt = *reinterpret_cast<const float4*>(y_true + base);
        int lbl = 0; float bv = yt.x;
        if (yt.y > bv) { bv = yt.y; lbl = 1; }
        if (yt.z > bv) { bv = yt.z; lbl = 2; }
        if (yt.w > bv) { bv = yt.w; lbl = 3; }

        float4 x = *reinterpret_cast<const float4*>(logits + base);
        float mx = fmaxf(fmaxf(x.x, x.y), fmaxf(x.z, x.w));
        float s = __expf(x.x - mx) + __expf(x.y - mx) + __expf(x.z - mx) + __expf(x.w - mx);
        float xl = (lbl == 0) ? x.x : (lbl == 1) ? x.y : (lbl == 2) ? x.z : x.w;
        ce += (xl - mx) - __logf(s);

        float4 p = *reinterpret_cast<const float4*>(prob + base);
        pred_alt[m] = p.y + p.z + p.w;
        // negative-entropy term, pair-independent part of JS
        float e = p.x * __logf(p.x + 1e-7f) + p.y * __logf(p.y + 1e-7f)
                + p.z * __logf(p.z + 1e-7f) + p.w * __logf(p.w + 1e-7f);
        ent[b * Ll + l] = e;
        lab[b * Ll + l] = (unsigned char)lbl;
        cnt += (lbl != 0);
    }

    float r2 = 0.f;
    if (cnt != 0 && cnt != 4) {
        float af = (float)cnt * 0.25f;
        float denom = fmaxf(af * (1.f - af), 0.01f);   // always > 0.01 here but keep exact
        float ssum = 0.f;
#pragma unroll
        for (int m = 0; m < 4; ++m) { float d = pred_alt[m] - af; ssum += d * d; }
        r2 = 0.25f * ssum / denom;
    }

    __shared__ float sce[4], sr2[4];
    int wid = threadIdx.x >> 6, lane = threadIdx.x & 63;
    float cew = waveSum(ce), r2w = waveSum(r2);
    if (lane == 0) { sce[wid] = cew; sr2[wid] = r2w; }
    __syncthreads();
    if (threadIdx.x == 0) {
        W[blockIdx.x]       = sce[0] + sce[1] + sce[2] + sce[3];
        W[128 + blockIdx.x] = sr2[0] + sr2[1] + sr2[2] + sr2[3];
    }
    // evo softmax row-sums, once
    if (blockIdx.x == 0 && threadIdx.x < Bb) {
        float s = 0.f;
        for (int k = 0; k < Bb; ++k) s += __expf(-y_evo[threadIdx.x * Bb + k]);
        W[ROWSUM_OFF + threadIdx.x] = s;
    }
}

__global__ __launch_bounds__(256) void kernelB(const float* __restrict__ prob,
                                               const float* __restrict__ y_evo,
                                               float* __restrict__ W) {
    int bx = blockIdx.x;
    int pair = bx >> 1;
    int chunk = bx & 1;

    int i = 0, rem = pair;
    while (rem >= (Bb - 1 - i)) { rem -= (Bb - 1 - i); ++i; }
    int j = i + 1 + rem;

    __shared__ float s_w;
    if (threadIdx.x == 0) {
        const float* rowsum = W + ROWSUM_OFF;
        s_w = __expf(-y_evo[i * Bb + j]) / (rowsum[i] + 1e-8f)
            + __expf(-y_evo[j * Bb + i]) / (rowsum[j] + 1e-8f);
    }
    __syncthreads();

    const float* ent = W + ENT_OFF;
    const unsigned char* lab = (const unsigned char*)(W + ENT_OFF + Bb * Ll);

    const int l0 = chunk * (Ll / 2);
    float a = 0.f;
    for (int l = l0 + threadIdx.x; l < l0 + Ll / 2; l += 256) {
        int oi = i * Ll + l, oj = j * Ll + l;
        unsigned char li = lab[oi], lj = lab[oj];
        float4 p = *reinterpret_cast<const float4*>(prob + oi * 4);
        float4 q = *reinterpret_cast<const float4*>(prob + oj * 4);
        float cross =
            (p.x + q.x) * __logf(0.5f * (p.x + q.x) + 1e-7f) +
            (p.y + q.y) * __logf(0.5f * (p.y + q.y) + 1e-7f) +
            (p.z + q.z) * __logf(0.5f * (p.z + q.z) + 1e-7f) +
            (p.w + q.w) * __logf(0.5f * (p.w + q.w) + 1e-7f);
        float js2 = ent[oi] + ent[oj] - cross;   // = kl_pm + kl_qm
        a += (li == lj) ? 0.5f * js2 : 0.f;
    }

    __shared__ float sp[4];
    int wid = threadIdx.x >> 6, lane = threadIdx.x & 63;
    float w = waveSum(a);
    if (lane == 0) sp[wid] = w;
    __syncthreads();
    if (threadIdx.x == 0)
        W[256 + bx] = s_w * (sp[0] + sp[1] + sp[2] + sp[3]);
}

__global__ __launch_bounds__(256) void kernelF(const float* __restrict__ W,
                                               float* __restrict__ out) {
    int tid = threadIdx.x;
    float ce = 0.f, r2 = 0.f, ev = 0.f;
    if (tid < 128) { ce = W[tid]; r2 = W[128 + tid]; }
    for (int k = tid; k < NBLK_B; k += 256) ev += W[256 + k];

    __shared__ float sc[4], sr[4], se[4];
    int wid = tid >> 6, lane = tid & 63;
    float c = waveSum(ce), r = waveSum(r2), e = waveSum(ev);
    if (lane == 0) { sc[wid] = c; sr[wid] = r; se[wid] = e; }
    __syncthreads();
    if (tid == 0) {
        float ces = sc[0] + sc[1] + sc[2] + sc[3];
        float r2s = sr[0] + sr[1] + sr[2] + sr[3];
        float evs = se[0] + se[1] + se[2] + se[3];
        if (!isfinite(evs)) evs = 0.f;
        out[0] = -ces - r2s * 0.125f + evs;
    }
}

extern "C" void kernel_launch(void* const* d_in, const int* in_sizes, int n_in,
                              void* d_out, int out_size, void* d_ws, size_t ws_size,
                              hipStream_t stream) {
    const float* logits = (const float*)d_in[0];
    const float* prob   = (const float*)d_in[1];
    const float* y_true = (const float*)d_in[2];
    const float* y_evo  = (const float*)d_in[3];
    float* out = (float*)d_out;
    float* W   = (float*)d_ws;

    kernelA<<<(8 * Ll) / 256, 256, 0, stream>>>(logits, prob, y_true, y_evo, W);
    kernelB<<<NBLK_B, 256, 0, stream>>>(prob, y_evo, W);
    kernelF<<<1, 256, 0, stream>>>(W, out);
}